// Round 3
// baseline (640.630 us; speedup 1.0000x reference)
//
#include <hip/hip_runtime.h>

#define NG 20000
#define BOFF 12800000u   // flat-index offset of batch b+32: 32*K*N = 32*20*20000

// ---------- JAX threefry2x32, key = (0, 42) ----------
__device__ __forceinline__ void threefry2x32(unsigned x0, unsigned x1,
                                             unsigned& o0, unsigned& o1) {
  const unsigned ks0 = 0u;
  const unsigned ks1 = 42u;
  const unsigned ks2 = 0x1BD11BDAu ^ 0u ^ 42u;
  x0 += ks0; x1 += ks1;
#define TFR(r) { x0 += x1; x1 = (x1 << (r)) | (x1 >> (32 - (r))); x1 ^= x0; }
  TFR(13) TFR(15) TFR(26) TFR(6)
  x0 += ks1; x1 += ks2 + 1u;
  TFR(17) TFR(29) TFR(16) TFR(24)
  x0 += ks2; x1 += ks0 + 2u;
  TFR(13) TFR(15) TFR(26) TFR(6)
  x0 += ks0; x1 += ks1 + 3u;
  TFR(17) TFR(29) TFR(16) TFR(24)
  x0 += ks1; x1 += ks2 + 4u;
  TFR(13) TFR(15) TFR(26) TFR(6)
  x0 += ks2; x1 += ks0 + 5u;
#undef TFR
  o0 = x0; o1 = x1;
}

// JAX >=0.5 default: threefry_partitionable. Per-element u64 counter i
// (hi=0 here since B*K*N < 2^32); 32-bit output word = bits1 ^ bits2.
__device__ __forceinline__ unsigned tfbits(unsigned ctr) {
  unsigned o0, o1;
  threefry2x32(0u, ctr, o0, o1);
  return o0 ^ o1;
}

// fp32 fast screen gumbel (v_log_f32 path): abs error vs fp64 ~1e-6
__device__ __forceinline__ float gumbel32(unsigned bits) {
  float f = __uint_as_float((bits >> 9) | 0x3f800000u) - 1.0f;
  float u = fmaxf(f, 1.17549435e-38f);
  return -logf(-logf(u));
}

// exact-path fp64 gumbel; u is a 23-bit dyadic rational, exact in double
__device__ __forceinline__ double gumbel64(unsigned bits) {
  float f = __uint_as_float((bits >> 9) | 0x3f800000u) - 1.0f;
  double u = (double)fmaxf(f, 1.17549435e-38f);   // fp32 tiny = 2^-126, exact
  return -log(-log(u));
}

// pack fp64 score (top 49 monotone bits) + 15-bit index; u64-max == (score, then smaller n)
__device__ __forceinline__ unsigned long long packcell(double v, int n) {
  unsigned long long u = (unsigned long long)__double_as_longlong(v);
  u = (u >> 63) ? ~u : (u | 0x8000000000000000ull);
  return (u & 0xFFFFFFFFFFFF8000ull) | (unsigned long long)(32767 - n);
}

// ---------- prep (fp64 selection path): Wf=Wk@W1k, Q, qb; zero cells ----------
__global__ __launch_bounds__(128) void kprep(
    const float* __restrict__ pe, const float* __restrict__ Wq,
    const float* __restrict__ bq, const float* __restrict__ Wk,
    const float* __restrict__ bk, const float* __restrict__ W1,
    const float* __restrict__ b1, double* __restrict__ Wfd,
    double* __restrict__ qbd, float* __restrict__ Qm,
    unsigned long long* __restrict__ cells) {
  __shared__ float L[512];
  __shared__ double Ld[128];
  const int t = threadIdx.x;
  const int bid = blockIdx.x;
  if (bid < 256) {
    // Wfd[f=bid, t] = sum_j Wk[f,j] * W1[128+j, t]   (fp64)
    L[t] = Wk[bid * 128 + t];
    __syncthreads();
    double acc = 0.0;
    #pragma unroll 8
    for (int j = 0; j < 128; ++j)
      acc = fma((double)L[j], (double)W1[(128 + j) * 128 + t], acc);
    Wfd[bid * 128 + t] = acc;
  } else if (bid < 320) {
    const int b = bid - 256;
    #pragma unroll
    for (int i = 0; i < 4; ++i) L[t + 128 * i] = pe[b * 512 + t + 128 * i];
    __syncthreads();
    double q = (double)bq[t];
    #pragma unroll 4
    for (int f = 0; f < 512; ++f)
      q = fma((double)L[f], (double)Wq[f * 128 + t], q);
    Qm[b * 128 + t] = (float)q;   // epilogue path stays fp32
    Ld[t] = q;
    __syncthreads();
    // qbd = Q@W1[:128] + b1 + bk@W1[128:]   (b2 dropped: uniform over n)
    double acc = (double)b1[t];
    #pragma unroll 4
    for (int j = 0; j < 128; ++j) {
      acc = fma(Ld[j], (double)W1[j * 128 + t], acc);
      acc = fma((double)bk[j], (double)W1[(128 + j) * 128 + t], acc);
    }
    qbd[b * 128 + t] = acc;
  } else {
    for (int i = t; i < 1280; i += 128) cells[i] = 0ull;
  }
}

// ---------- kp = ge @ Wf   [20000,256]x[256,128] in fp64 ----------
__global__ __launch_bounds__(128) void kgemm(
    const float* __restrict__ ge, const double* __restrict__ Wfd,
    double* __restrict__ kpd) {
  const int t = threadIdx.x;          // d = t
  const int g0 = blockIdx.x * 16;     // 1250 blocks * 16 genes
  const float* gb = ge + (size_t)g0 * 256;
  double acc[16];
  #pragma unroll
  for (int g = 0; g < 16; ++g) acc[g] = 0.0;
  for (int f = 0; f < 256; f += 4) {
    const double w0 = Wfd[(f + 0) * 128 + t];
    const double w1 = Wfd[(f + 1) * 128 + t];
    const double w2_ = Wfd[(f + 2) * 128 + t];
    const double w3 = Wfd[(f + 3) * 128 + t];
    #pragma unroll
    for (int g = 0; g < 16; ++g) {
      const float4 gv = *(const float4*)(gb + (size_t)g * 256 + f);  // uniform -> s_load
      acc[g] = fma((double)gv.x, w0, acc[g]);
      acc[g] = fma((double)gv.y, w1, acc[g]);
      acc[g] = fma((double)gv.z, w2_, acc[g]);
      acc[g] = fma((double)gv.w, w3, acc[g]);
    }
  }
  #pragma unroll
  for (int g = 0; g < 16; ++g)
    kpd[(size_t)(g0 + g) * 128 + t] = acc[g];
}

// ---------- selection (fp64 scores): sim + gumbel + argmax -> packed atomic cells ----------
// wave = one b-pair (p, p+32) at a time; lane holds dims d=2*lane, 2*lane+1.
__global__ __launch_bounds__(256) void ksel(
    const double* __restrict__ kpd, const double* __restrict__ qbd,
    const float* __restrict__ w2, unsigned long long* __restrict__ cells) {
  const int t = threadIdx.x;
  const int wv = t >> 6;
  const int lane = t & 63;
  const int n0 = blockIdx.x * 24;     // 834 blocks * 24 genes
  const int k = lane % 20;            // gumbel slot (lanes < 60 active)
  const int gi = lane / 20;
  const double w2x = (double)w2[2 * lane];
  const double w2y = (double)w2[2 * lane + 1];

  for (int pp = 0; pp < 8; ++pp) {
    const int p = wv * 8 + pp;        // pair id 0..31 -> batches (p, p+32)
    const double2 qA = ((const double2*)(qbd + p * 128))[lane];
    const double2 qB = ((const double2*)(qbd + (p + 32) * 128))[lane];
    double bvA = -1e300, bvB = -1e300;
    int bnA = 0, bnB = 0;
    for (int grp = 0; grp < 8; ++grp) {
      double sA[3], sB[3];
      #pragma unroll
      for (int g3 = 0; g3 < 3; ++g3) {
        const int n = n0 + grp * 3 + g3;
        double a, c;
        if (n < NG) {   // wave-uniform branch
          const double2 kv = ((const double2*)(kpd + (size_t)n * 128))[lane];
          const double t0 = qA.x + kv.x, t1 = qA.y + kv.y;
          const double u0 = qB.x + kv.x, u1 = qB.y + kv.y;
          a = fmax(t0, 0.1 * t0) * w2x + fmax(t1, 0.1 * t1) * w2y;
          c = fmax(u0, 0.1 * u0) * w2x + fmax(u1, 0.1 * u1) * w2y;
          #pragma unroll
          for (int off = 32; off; off >>= 1) {
            a += __shfl_xor(a, off, 64);
            c += __shfl_xor(c, off, 64);
          }
        } else { a = -1e300; c = -1e300; }
        sA[g3] = a; sB[g3] = c;
      }
      // gumbel phase: lane l<60 handles (k = l%20, gene slot gi = l/20)
      const int n = n0 + grp * 3 + gi;
      const double simA = (gi == 0) ? sA[0] : ((gi == 1) ? sA[1] : sA[2]);
      const double simB = (gi == 0) ? sB[0] : ((gi == 1) ? sB[1] : sB[2]);
      if (lane < 60 && n < NG) {
        const unsigned idxA = (unsigned)(p * 20 + k) * (unsigned)NG + (unsigned)n;
        // fp32 screen (margin 1e-4 >> ~1e-6 screen error), fp64 exact only when contending
        const unsigned bA = tfbits(idxA);
        const double scrA = 2.0 * simA + (double)gumbel32(bA);
        if (scrA + 1e-4 > bvA) {
          const double e = 2.0 * simA + gumbel64(bA);
          if (e > bvA) { bvA = e; bnA = n; }   // strict >: first-max (smaller n) wins
        }
        const unsigned bB = tfbits(idxA + BOFF);   // batch p+32, same (k, n)
        const double scrB = 2.0 * simB + (double)gumbel32(bB);
        if (scrB + 1e-4 > bvB) {
          const double e = 2.0 * simB + gumbel64(bB);
          if (e > bvB) { bvB = e; bnB = n; }
        }
      }
    }
    // pack (score,index) and fold gi-slots: lanes<20 merge lanes +20, +40
    unsigned long long pA = packcell(bvA, bnA);
    unsigned long long pB = packcell(bvB, bnB);
    #pragma unroll
    for (int sh = 20; sh <= 40; sh += 20) {
      const unsigned long long oA = __shfl(pA, lane + sh, 64);
      const unsigned long long oB = __shfl(pB, lane + sh, 64);
      if (lane < 20) {
        if (oA > pA) pA = oA;
        if (oB > pB) pB = oB;
      }
    }
    if (lane < 20) {
      atomicMax(&cells[p * 20 + lane], pA);
      atomicMax(&cells[(p + 32) * 20 + lane], pB);
    }
  }
}

// ---------- epilogue (fp32): gather-V on the fly, scores, softmax over K, context ----------
__global__ __launch_bounds__(256) void kfinal(
    const float* __restrict__ ge, const float* __restrict__ Wv,
    const float* __restrict__ bv, const float* __restrict__ Qm,
    const unsigned long long* __restrict__ cells, float* __restrict__ out) {
  const int b = blockIdx.x;
  const int t = threadIdx.x;
  const int wv = t >> 6;
  const int lane = t & 63;
  __shared__ float sc[20];
  __shared__ float ctxp[4][128];
  const float2 qv = ((const float2*)(Qm + b * 128))[lane];
  const float2 bvv = ((const float2*)bv)[lane];
  float2 Vk[5];
  #pragma unroll
  for (int kk = 0; kk < 5; ++kk) {
    const int kkk = wv * 5 + kk;
    const unsigned long long cell = cells[b * 20 + kkk];
    const int n = 32767 - (int)(cell & 0x7FFFull);
    const float* gr = ge + (size_t)n * 256;
    float v0 = bvv.x, v1 = bvv.y;
    for (int f = 0; f < 256; f += 4) {
      const float4 gv = *(const float4*)(gr + f);   // uniform -> s_load
      const float2 w0 = ((const float2*)(Wv + (size_t)(f + 0) * 128))[lane];
      const float2 w1 = ((const float2*)(Wv + (size_t)(f + 1) * 128))[lane];
      const float2 w2_ = ((const float2*)(Wv + (size_t)(f + 2) * 128))[lane];
      const float2 w3 = ((const float2*)(Wv + (size_t)(f + 3) * 128))[lane];
      v0 = fmaf(gv.x, w0.x, v0); v1 = fmaf(gv.x, w0.y, v1);
      v0 = fmaf(gv.y, w1.x, v0); v1 = fmaf(gv.y, w1.y, v1);
      v0 = fmaf(gv.z, w2_.x, v0); v1 = fmaf(gv.z, w2_.y, v1);
      v0 = fmaf(gv.w, w3.x, v0); v1 = fmaf(gv.w, w3.y, v1);
    }
    Vk[kk] = make_float2(v0, v1);
    float pr = qv.x * v0 + qv.y * v1;
    #pragma unroll
    for (int off = 32; off; off >>= 1) pr += __shfl_xor(pr, off, 64);
    if (lane == 0) sc[kkk] = pr * 0.08838834764831845f;  // 1/sqrt(128)
  }
  __syncthreads();
  float m = -3.0e38f;
  #pragma unroll
  for (int i = 0; i < 20; ++i) m = fmaxf(m, sc[i]);
  float s = 0.f;
  #pragma unroll
  for (int i = 0; i < 20; ++i) s += expf(sc[i] - m);
  const float inv = 1.0f / s;
  float c0 = 0.f, c1 = 0.f;
  #pragma unroll
  for (int kk = 0; kk < 5; ++kk) {
    const float wk = expf(sc[wv * 5 + kk] - m) * inv;
    c0 = fmaf(wk, Vk[kk].x, c0);
    c1 = fmaf(wk, Vk[kk].y, c1);
  }
  ctxp[wv][2 * lane] = c0;
  ctxp[wv][2 * lane + 1] = c1;
  __syncthreads();
  if (t < 128)
    out[b * 128 + t] = (ctxp[0][t] + ctxp[1][t]) + (ctxp[2][t] + ctxp[3][t]);
}

extern "C" void kernel_launch(void* const* d_in, const int* in_sizes, int n_in,
                              void* d_out, int out_size, void* d_ws, size_t ws_size,
                              hipStream_t stream) {
  (void)in_sizes; (void)n_in; (void)out_size; (void)ws_size;
  const float* pe = (const float*)d_in[0];
  const float* ge = (const float*)d_in[1];
  const float* Wq = (const float*)d_in[2];
  const float* bq = (const float*)d_in[3];
  const float* Wk = (const float*)d_in[4];
  const float* bk = (const float*)d_in[5];
  const float* Wv = (const float*)d_in[6];
  const float* bvp = (const float*)d_in[7];
  const float* W1 = (const float*)d_in[8];
  const float* b1 = (const float*)d_in[9];
  const float* w2 = (const float*)d_in[10];
  // d_in[11] = b2: uniform over n -> cancels in argmax; absent from output path.

  char* w = (char*)d_ws;
  double* Wfd = (double*)w;                              // 262144 B
  double* qbd = (double*)(w + 262144);                   // 65536 B
  float* Qm = (float*)(w + 327680);                      // 32768 B
  unsigned long long* cells =
      (unsigned long long*)(w + 360448);                 // 10240 B
  double* kpd = (double*)(w + 370688);                   // 20,480,000 B  (~20.9 MB total)
  float* out = (float*)d_out;

  kprep<<<dim3(321), dim3(128), 0, stream>>>(pe, Wq, bq, Wk, bk, W1, b1,
                                             Wfd, qbd, Qm, cells);
  kgemm<<<dim3(1250), dim3(128), 0, stream>>>(ge, Wfd, kpd);
  ksel<<<dim3(834), dim3(256), 0, stream>>>(kpd, qbd, w2, cells);
  kfinal<<<dim3(64), dim3(256), 0, stream>>>(ge, Wv, bvp, Qm, cells, out);
}

// Round 4
// 529.846 us; speedup vs baseline: 1.2091x; 1.2091x over previous
//
#include <hip/hip_runtime.h>

#define NG 20000
#define BOFF 12800000u   // flat-index offset of batch b+32: 32*K*N

// ---------- JAX threefry2x32, key = (0, 42) ----------
__device__ __forceinline__ void threefry2x32(unsigned x0, unsigned x1,
                                             unsigned& o0, unsigned& o1) {
  const unsigned ks0 = 0u;
  const unsigned ks1 = 42u;
  const unsigned ks2 = 0x1BD11BDAu ^ 0u ^ 42u;
  x0 += ks0; x1 += ks1;
#define TFR(r) { x0 += x1; x1 = (x1 << (r)) | (x1 >> (32 - (r))); x1 ^= x0; }
  TFR(13) TFR(15) TFR(26) TFR(6)
  x0 += ks1; x1 += ks2 + 1u;
  TFR(17) TFR(29) TFR(16) TFR(24)
  x0 += ks2; x1 += ks0 + 2u;
  TFR(13) TFR(15) TFR(26) TFR(6)
  x0 += ks0; x1 += ks1 + 3u;
  TFR(17) TFR(29) TFR(16) TFR(24)
  x0 += ks1; x1 += ks2 + 4u;
  TFR(13) TFR(15) TFR(26) TFR(6)
  x0 += ks2; x1 += ks0 + 5u;
#undef TFR
  o0 = x0; o1 = x1;
}

// JAX threefry_partitionable: bits(i) = o0 ^ o1 of threefry((0,42),(0,i))
__device__ __forceinline__ unsigned tfbits(unsigned ctr) {
  unsigned o0, o1;
  threefry2x32(0u, ctr, o0, o1);
  return o0 ^ o1;
}

// fp32 fast-screen gumbel (hw log path); abs err vs fp64 < ~4e-6; sup < 15.95
__device__ __forceinline__ float gumbel32(unsigned bits) {
  float f = __uint_as_float((bits >> 9) | 0x3f800000u) - 1.0f;
  float u = fmaxf(f, 1.17549435e-38f);
  return -__logf(-__logf(u));
}

// exact fp64 gumbel; u is a 23-bit dyadic rational, exact in double
__device__ __forceinline__ double gumbel64(unsigned bits) {
  float f = __uint_as_float((bits >> 9) | 0x3f800000u) - 1.0f;
  double u = (double)fmaxf(f, 1.17549435e-38f);
  return -log(-log(u));
}

// pack fp64 score (top 49 monotone bits) + 15-bit (32767-n): u64 max == (score, then smaller n)
__device__ __forceinline__ unsigned long long packcell(double v, int n) {
  unsigned long long u = (unsigned long long)__double_as_longlong(v);
  u = (u >> 63) ? ~u : (u | 0x8000000000000000ull);
  return (u & 0xFFFFFFFFFFFF8000ull) | (unsigned long long)(32767 - n);
}

// ---------- prep: Wf=Wk@W1k (fp64), Q, qbT (d-major, fp64); zero cells ----------
__global__ __launch_bounds__(128) void kprep(
    const float* __restrict__ pe, const float* __restrict__ Wq,
    const float* __restrict__ bq, const float* __restrict__ Wk,
    const float* __restrict__ bk, const float* __restrict__ W1,
    const float* __restrict__ b1, double* __restrict__ Wfd,
    double* __restrict__ qbT, float* __restrict__ Qm,
    unsigned long long* __restrict__ cells) {
  __shared__ float L[512];
  __shared__ double Ld[128];
  const int t = threadIdx.x;
  const int bid = blockIdx.x;
  if (bid < 256) {
    L[t] = Wk[bid * 128 + t];
    __syncthreads();
    double acc = 0.0;
    #pragma unroll 8
    for (int j = 0; j < 128; ++j)
      acc = fma((double)L[j], (double)W1[(128 + j) * 128 + t], acc);
    Wfd[bid * 128 + t] = acc;
  } else if (bid < 320) {
    const int b = bid - 256;
    #pragma unroll
    for (int i = 0; i < 4; ++i) L[t + 128 * i] = pe[b * 512 + t + 128 * i];
    __syncthreads();
    double q = (double)bq[t];
    #pragma unroll 4
    for (int f = 0; f < 512; ++f)
      q = fma((double)L[f], (double)Wq[f * 128 + t], q);
    Qm[b * 128 + t] = (float)q;   // epilogue path stays fp32
    Ld[t] = q;
    __syncthreads();
    // qb[b,d=t] = Q@W1[:128] + b1 + bk@W1[128:]; store transposed qbT[d][b]
    double acc = (double)b1[t];
    #pragma unroll 4
    for (int j = 0; j < 128; ++j) {
      acc = fma(Ld[j], (double)W1[j * 128 + t], acc);
      acc = fma((double)bk[j], (double)W1[(128 + j) * 128 + t], acc);
    }
    qbT[t * 64 + b] = acc;
  } else {
    for (int i = t; i < 1280; i += 128) cells[i] = 0ull;
  }
}

// ---------- kp = ge @ Wf   [20000,256]x[256,128] fp64 ----------
__global__ __launch_bounds__(128) void kgemm(
    const float* __restrict__ ge, const double* __restrict__ Wfd,
    double* __restrict__ kpd) {
  const int t = threadIdx.x;          // d = t
  const int g0 = blockIdx.x * 16;     // 1250 blocks * 16 genes
  const float* gb = ge + (size_t)g0 * 256;
  double acc[16];
  #pragma unroll
  for (int g = 0; g < 16; ++g) acc[g] = 0.0;
  for (int f = 0; f < 256; f += 4) {
    const double w0 = Wfd[(f + 0) * 128 + t];
    const double w1 = Wfd[(f + 1) * 128 + t];
    const double w2_ = Wfd[(f + 2) * 128 + t];
    const double w3 = Wfd[(f + 3) * 128 + t];
    #pragma unroll
    for (int g = 0; g < 16; ++g) {
      const float4 gv = *(const float4*)(gb + (size_t)g * 256 + f);  // uniform -> s_load
      acc[g] = fma((double)gv.x, w0, acc[g]);
      acc[g] = fma((double)gv.y, w1, acc[g]);
      acc[g] = fma((double)gv.z, w2_, acc[g]);
      acc[g] = fma((double)gv.w, w3, acc[g]);
    }
  }
  #pragma unroll
  for (int g = 0; g < 16; ++g)
    kpd[(size_t)(g0 + g) * 128 + t] = acc[g];
}

// ---------- sim[b][n] = sum_d leaky(qb[b,d]+kp[n,d])*w2[d]  (fp64, no shuffles) ----------
// leaky(t)*w2 == t*(0.55*w2) + |t|*(0.45*w2); |t| is a free input modifier.
__global__ __launch_bounds__(64) void ksim(
    const double* __restrict__ kpd, const double* __restrict__ qbT,
    const float* __restrict__ w2, double* __restrict__ simd) {
  const int lane = threadIdx.x;
  const int n = blockIdx.x * 64 + lane;           // 313 x-blocks
  const int b0 = blockIdx.y * 8;                  // 8 y-blocks * 8 batches
  const size_t nro = (size_t)min(n, NG - 1) * 128;
  double acc[8];
  #pragma unroll
  for (int j = 0; j < 8; ++j) acc[j] = 0.0;
  for (int d = 0; d < 128; ++d) {
    const double kv = kpd[nro + d];               // lane-rows; L1-resident lines
    const double w2d = (double)w2[d];
    const double c1 = 0.55 * w2d, c2 = 0.45 * w2d;
    const double* qr = qbT + d * 64 + b0;         // block-uniform -> s_load
    #pragma unroll
    for (int j = 0; j < 8; ++j) {
      const double tt = qr[j] + kv;
      acc[j] = fma(tt, c1, acc[j]);
      acc[j] = fma(fabs(tt), c2, acc[j]);
    }
  }
  if (n < NG) {
    #pragma unroll
    for (int j = 0; j < 8; ++j) simd[(size_t)(b0 + j) * NG + n] = acc[j];
  }
}

// ---------- selection: two-pass screen/exact over precomputed sims ----------
// wave owns pair p (batches p, p+32); lane = (k = lane%20, gi = lane/20<3);
// chunk of 313 genes per block; gumbel sup bound 15.95 prunes threefry.
__global__ __launch_bounds__(256) void ksel2(
    const double* __restrict__ simd, unsigned long long* __restrict__ cells) {
  const int t = threadIdx.x;
  const int wv = t >> 6;
  const int lane = t & 63;
  const int p = (blockIdx.x & 7) * 4 + wv;        // pair 0..31
  const int c = blockIdx.x >> 3;                  // chunk 0..63
  const int n0 = c * 313;
  const int nEnd = min(n0 + 313, NG);
  const int k = lane % 20;
  const int gi = lane / 20;
  const bool active = lane < 60;
  const double* srA = simd + (size_t)p * NG;
  const double* srB = simd + (size_t)(p + 32) * NG;
  const unsigned kbase = (unsigned)(p * 20 + k) * (unsigned)NG;

  // pass 1: fp32 screen max (no index tracking)
  float mA = -3.0e38f, mB = -3.0e38f;
  for (int it = 0; it < 105; ++it) {
    const int n = n0 + it * 3 + gi;
    const bool v = active && (n < nEnd);
    const int nc = v ? n : n0;
    const float sA2 = (float)(2.0 * srA[nc]);
    const float sB2 = (float)(2.0 * srB[nc]);
    const unsigned idxA = kbase + (unsigned)nc;
    if (v && sA2 + 15.95f > mA)
      mA = fmaxf(mA, sA2 + gumbel32(tfbits(idxA)));
    if (v && sB2 + 15.95f > mB)
      mB = fmaxf(mB, sB2 + gumbel32(tfbits(idxA + BOFF)));
  }

  // pass 2: exact fp64 for candidates within margin of the screen max
  const float thA = mA - 1e-3f, thB = mB - 1e-3f;  // margin >> 2e-5 screen err
  unsigned long long pbA = 0ull, pbB = 0ull;
  for (int it = 0; it < 105; ++it) {
    const int n = n0 + it * 3 + gi;
    const bool v = active && (n < nEnd);
    const int nc = v ? n : n0;
    const double sA = srA[nc], sB = srB[nc];
    const unsigned idxA = kbase + (unsigned)nc;
    if (v && (float)(2.0 * sA) + 15.95f > thA) {
      const unsigned bb = tfbits(idxA);
      if ((float)(2.0 * sA) + gumbel32(bb) > thA) {
        const unsigned long long u = packcell(2.0 * sA + gumbel64(bb), n);
        if (u > pbA) pbA = u;
      }
    }
    if (v && (float)(2.0 * sB) + 15.95f > thB) {
      const unsigned bb = tfbits(idxA + BOFF);
      if ((float)(2.0 * sB) + gumbel32(bb) > thB) {
        const unsigned long long u = packcell(2.0 * sB + gumbel64(bb), n);
        if (u > pbB) pbB = u;
      }
    }
  }
  // fold gi slots (lanes +20, +40), then one atomic per (batch, k)
  #pragma unroll
  for (int sh = 20; sh <= 40; sh += 20) {
    const unsigned long long oA = __shfl(pbA, lane + sh, 64);
    const unsigned long long oB = __shfl(pbB, lane + sh, 64);
    if (lane < 20) {
      if (oA > pbA) pbA = oA;
      if (oB > pbB) pbB = oB;
    }
  }
  if (lane < 20 && pbA) atomicMax(&cells[p * 20 + lane], pbA);
  if (lane < 20 && pbB) atomicMax(&cells[(p + 32) * 20 + lane], pbB);
}

// ---------- epilogue (fp32): gather-V on the fly, scores, softmax over K, context ----------
__global__ __launch_bounds__(256) void kfinal(
    const float* __restrict__ ge, const float* __restrict__ Wv,
    const float* __restrict__ bv, const float* __restrict__ Qm,
    const unsigned long long* __restrict__ cells, float* __restrict__ out) {
  const int b = blockIdx.x;
  const int t = threadIdx.x;
  const int wv = t >> 6;
  const int lane = t & 63;
  __shared__ float sc[20];
  __shared__ float ctxp[4][128];
  const float2 qv = ((const float2*)(Qm + b * 128))[lane];
  const float2 bvv = ((const float2*)bv)[lane];
  float2 Vk[5];
  #pragma unroll
  for (int kk = 0; kk < 5; ++kk) {
    const int kkk = wv * 5 + kk;
    const unsigned long long cell = cells[b * 20 + kkk];
    const int n = 32767 - (int)(cell & 0x7FFFull);
    const float* gr = ge + (size_t)n * 256;
    float v0 = bvv.x, v1 = bvv.y;
    for (int f = 0; f < 256; f += 4) {
      const float4 gv = *(const float4*)(gr + f);   // uniform -> s_load
      const float2 w0 = ((const float2*)(Wv + (size_t)(f + 0) * 128))[lane];
      const float2 w1 = ((const float2*)(Wv + (size_t)(f + 1) * 128))[lane];
      const float2 w2_ = ((const float2*)(Wv + (size_t)(f + 2) * 128))[lane];
      const float2 w3 = ((const float2*)(Wv + (size_t)(f + 3) * 128))[lane];
      v0 = fmaf(gv.x, w0.x, v0); v1 = fmaf(gv.x, w0.y, v1);
      v0 = fmaf(gv.y, w1.x, v0); v1 = fmaf(gv.y, w1.y, v1);
      v0 = fmaf(gv.z, w2_.x, v0); v1 = fmaf(gv.z, w2_.y, v1);
      v0 = fmaf(gv.w, w3.x, v0); v1 = fmaf(gv.w, w3.y, v1);
    }
    Vk[kk] = make_float2(v0, v1);
    float pr = qv.x * v0 + qv.y * v1;
    #pragma unroll
    for (int off = 32; off; off >>= 1) pr += __shfl_xor(pr, off, 64);
    if (lane == 0) sc[kkk] = pr * 0.08838834764831845f;  // 1/sqrt(128)
  }
  __syncthreads();
  float m = -3.0e38f;
  #pragma unroll
  for (int i = 0; i < 20; ++i) m = fmaxf(m, sc[i]);
  float s = 0.f;
  #pragma unroll
  for (int i = 0; i < 20; ++i) s += expf(sc[i] - m);
  const float inv = 1.0f / s;
  float c0 = 0.f, c1 = 0.f;
  #pragma unroll
  for (int kk = 0; kk < 5; ++kk) {
    const float wk = expf(sc[wv * 5 + kk] - m) * inv;
    c0 = fmaf(wk, Vk[kk].x, c0);
    c1 = fmaf(wk, Vk[kk].y, c1);
  }
  ctxp[wv][2 * lane] = c0;
  ctxp[wv][2 * lane + 1] = c1;
  __syncthreads();
  if (t < 128)
    out[b * 128 + t] = (ctxp[0][t] + ctxp[1][t]) + (ctxp[2][t] + ctxp[3][t]);
}

extern "C" void kernel_launch(void* const* d_in, const int* in_sizes, int n_in,
                              void* d_out, int out_size, void* d_ws, size_t ws_size,
                              hipStream_t stream) {
  (void)in_sizes; (void)n_in; (void)out_size; (void)ws_size;
  const float* pe = (const float*)d_in[0];
  const float* ge = (const float*)d_in[1];
  const float* Wq = (const float*)d_in[2];
  const float* bq = (const float*)d_in[3];
  const float* Wk = (const float*)d_in[4];
  const float* bk = (const float*)d_in[5];
  const float* Wv = (const float*)d_in[6];
  const float* bvp = (const float*)d_in[7];
  const float* W1 = (const float*)d_in[8];
  const float* b1 = (const float*)d_in[9];
  const float* w2 = (const float*)d_in[10];
  // d_in[11] = b2: uniform over n -> cancels in argmax; absent from output path.

  char* w = (char*)d_ws;
  double* Wfd = (double*)w;                              // 262144 B
  double* qbT = (double*)(w + 262144);                   // 65536 B
  float* Qm = (float*)(w + 327680);                      // 32768 B
  unsigned long long* cells =
      (unsigned long long*)(w + 360448);                 // 10240 B
  double* kpd = (double*)(w + 370688);                   // 20,480,000 B
  double* simd = (double*)(w + 20850688);                // 10,240,000 B (~31.1 MB total)
  float* out = (float*)d_out;

  kprep<<<dim3(321), dim3(128), 0, stream>>>(pe, Wq, bq, Wk, bk, W1, b1,
                                             Wfd, qbT, Qm, cells);
  kgemm<<<dim3(1250), dim3(128), 0, stream>>>(ge, Wfd, kpd);
  ksim<<<dim3(313, 8), dim3(64), 0, stream>>>(kpd, qbT, w2, simd);
  ksel2<<<dim3(512), dim3(256), 0, stream>>>(simd, cells);
  kfinal<<<dim3(64), dim3(256), 0, stream>>>(ge, Wv, bvp, Qm, cells, out);
}

// Round 5
// 384.034 us; speedup vs baseline: 1.6682x; 1.3797x over previous
//
#include <hip/hip_runtime.h>

#define NG 20000
#define BOFF 12800000u   // flat-index offset of batch b+32: 32*K*N

// ---------- JAX threefry2x32, key = (0, 42) ----------
__device__ __forceinline__ void threefry2x32(unsigned x0, unsigned x1,
                                             unsigned& o0, unsigned& o1) {
  const unsigned ks0 = 0u;
  const unsigned ks1 = 42u;
  const unsigned ks2 = 0x1BD11BDAu ^ 0u ^ 42u;
  x0 += ks0; x1 += ks1;
#define TFR(r) { x0 += x1; x1 = (x1 << (r)) | (x1 >> (32 - (r))); x1 ^= x0; }
  TFR(13) TFR(15) TFR(26) TFR(6)
  x0 += ks1; x1 += ks2 + 1u;
  TFR(17) TFR(29) TFR(16) TFR(24)
  x0 += ks2; x1 += ks0 + 2u;
  TFR(13) TFR(15) TFR(26) TFR(6)
  x0 += ks0; x1 += ks1 + 3u;
  TFR(17) TFR(29) TFR(16) TFR(24)
  x0 += ks1; x1 += ks2 + 4u;
  TFR(13) TFR(15) TFR(26) TFR(6)
  x0 += ks2; x1 += ks0 + 5u;
#undef TFR
  o0 = x0; o1 = x1;
}

// JAX threefry_partitionable: bits(i) = o0 ^ o1 of threefry((0,42),(0,i))
__device__ __forceinline__ unsigned tfbits(unsigned ctr) {
  unsigned o0, o1;
  threefry2x32(0u, ctr, o0, o1);
  return o0 ^ o1;
}

// fp32 fast-screen gumbel (hw log path); abs err vs fp64 < ~1e-5
__device__ __forceinline__ float gumbel32(unsigned bits) {
  float f = __uint_as_float((bits >> 9) | 0x3f800000u) - 1.0f;
  float u = fmaxf(f, 1.17549435e-38f);
  return -__logf(-__logf(u));
}

// exact fp64 gumbel; u is a 23-bit dyadic rational, exact in double
__device__ __forceinline__ double gumbel64(unsigned bits) {
  float f = __uint_as_float((bits >> 9) | 0x3f800000u) - 1.0f;
  double u = (double)fmaxf(f, 1.17549435e-38f);
  return -log(-log(u));
}

// pack fp64 score (top 49 monotone bits) + 15-bit (32767-n): u64 max == (score, then smaller n)
__device__ __forceinline__ unsigned long long packcell(double v, int n) {
  unsigned long long u = (unsigned long long)__double_as_longlong(v);
  u = (u >> 63) ? ~u : (u | 0x8000000000000000ull);
  return (u & 0xFFFFFFFFFFFF8000ull) | (unsigned long long)(32767 - n);
}

// ---------- prep: Wf=Wk@W1k (fp64), Q, qbT (d-major, fp64); zero cells ----------
__global__ __launch_bounds__(128) void kprep(
    const float* __restrict__ pe, const float* __restrict__ Wq,
    const float* __restrict__ bq, const float* __restrict__ Wk,
    const float* __restrict__ bk, const float* __restrict__ W1,
    const float* __restrict__ b1, double* __restrict__ Wfd,
    double* __restrict__ qbT, float* __restrict__ Qm,
    unsigned long long* __restrict__ cells) {
  __shared__ float L[512];
  __shared__ double Ld[128];
  const int t = threadIdx.x;
  const int bid = blockIdx.x;
  if (bid < 256) {
    L[t] = Wk[bid * 128 + t];
    __syncthreads();
    double acc = 0.0;
    #pragma unroll 8
    for (int j = 0; j < 128; ++j)
      acc = fma((double)L[j], (double)W1[(128 + j) * 128 + t], acc);
    Wfd[bid * 128 + t] = acc;
  } else if (bid < 320) {
    const int b = bid - 256;
    #pragma unroll
    for (int i = 0; i < 4; ++i) L[t + 128 * i] = pe[b * 512 + t + 128 * i];
    __syncthreads();
    double q = (double)bq[t];
    #pragma unroll 4
    for (int f = 0; f < 512; ++f)
      q = fma((double)L[f], (double)Wq[f * 128 + t], q);
    Qm[b * 128 + t] = (float)q;   // epilogue path stays fp32
    Ld[t] = q;
    __syncthreads();
    // qb[b,d=t] = Q@W1[:128] + b1 + bk@W1[128:]; store transposed qbT[d][b]
    double acc = (double)b1[t];
    #pragma unroll 4
    for (int j = 0; j < 128; ++j) {
      acc = fma(Ld[j], (double)W1[j * 128 + t], acc);
      acc = fma((double)bk[j], (double)W1[(128 + j) * 128 + t], acc);
    }
    qbT[t * 64 + b] = acc;
  } else {
    for (int i = t; i < 1280; i += 128) cells[i] = 0ull;
  }
}

// ---------- kp = ge @ Wf   [20000,256]x[256,128] fp64 ----------
__global__ __launch_bounds__(128) void kgemm(
    const float* __restrict__ ge, const double* __restrict__ Wfd,
    double* __restrict__ kpd) {
  const int t = threadIdx.x;          // d = t
  const int g0 = blockIdx.x * 16;     // 1250 blocks * 16 genes
  const float* gb = ge + (size_t)g0 * 256;
  double acc[16];
  #pragma unroll
  for (int g = 0; g < 16; ++g) acc[g] = 0.0;
  for (int f = 0; f < 256; f += 4) {
    const double w0 = Wfd[(f + 0) * 128 + t];
    const double w1 = Wfd[(f + 1) * 128 + t];
    const double w2_ = Wfd[(f + 2) * 128 + t];
    const double w3 = Wfd[(f + 3) * 128 + t];
    #pragma unroll
    for (int g = 0; g < 16; ++g) {
      const float4 gv = *(const float4*)(gb + (size_t)g * 256 + f);  // uniform -> s_load
      acc[g] = fma((double)gv.x, w0, acc[g]);
      acc[g] = fma((double)gv.y, w1, acc[g]);
      acc[g] = fma((double)gv.z, w2_, acc[g]);
      acc[g] = fma((double)gv.w, w3, acc[g]);
    }
  }
  #pragma unroll
  for (int g = 0; g < 16; ++g)
    kpd[(size_t)(g0 + g) * 128 + t] = acc[g];
}

// ---------- sim[b][n] = sum_d leaky(qb[b,d]+kp[n,d])*w2[d]  (fp64, no shuffles) ----------
// leaky(t)*w2 == t*(0.55*w2) + |t|*(0.45*w2)
__global__ __launch_bounds__(64) void ksim(
    const double* __restrict__ kpd, const double* __restrict__ qbT,
    const float* __restrict__ w2, double* __restrict__ simd) {
  const int lane = threadIdx.x;
  const int n = blockIdx.x * 64 + lane;           // 313 x-blocks
  const int b0 = blockIdx.y * 8;                  // 8 y-blocks * 8 batches
  const size_t nro = (size_t)min(n, NG - 1) * 128;
  double acc[8];
  #pragma unroll
  for (int j = 0; j < 8; ++j) acc[j] = 0.0;
  for (int d = 0; d < 128; ++d) {
    const double kv = kpd[nro + d];
    const double w2d = (double)w2[d];
    const double c1 = 0.55 * w2d, c2 = 0.45 * w2d;
    const double* qr = qbT + d * 64 + b0;         // block-uniform -> s_load
    #pragma unroll
    for (int j = 0; j < 8; ++j) {
      const double tt = qr[j] + kv;
      acc[j] = fma(tt, c1, acc[j]);
      acc[j] = fma(fabs(tt), c2, acc[j]);
    }
  }
  if (n < NG) {
    #pragma unroll
    for (int j = 0; j < 8; ++j) simd[(size_t)(b0 + j) * NG + n] = acc[j];
  }
}

// ---------- selection: single-pass fp32 top-2 screen, fp64 exact at end ----------
// wave owns pair p (batches p, p+32); lane = (k = lane%20, gi = lane/20 < 3);
// 247 chunks * 81 genes; 1976 blocks -> ~7.7 waves/SIMD.
__global__ __launch_bounds__(256) void ksel2(
    const double* __restrict__ simd, unsigned long long* __restrict__ cells) {
  const int t = threadIdx.x;
  const int wv = t >> 6;
  const int lane = t & 63;
  const int p = (int)(blockIdx.x & 7) * 4 + wv;   // pair 0..31
  const int c = (int)(blockIdx.x >> 3);           // chunk 0..246
  const int n0 = c * 81;
  const int nEnd = min(n0 + 81, NG);
  const int k = lane % 20;
  const int gi = lane / 20;
  const bool active = lane < 60;
  const double* sdA = simd + (size_t)p * NG;
  const double* sdB = simd + (size_t)(p + 32) * NG;
  const unsigned kbase = (unsigned)(p * 20 + k) * (unsigned)NG;

  float m1A = -3e38f, m2A = -3e38f, m1B = -3e38f, m2B = -3e38f;
  int n1A = -1, n2A = -1, n1B = -1, n2B = -1;
  unsigned c1A = 0, c2A = 0, c1B = 0, c2B = 0;

  for (int it = 0; it < 27; ++it) {
    const int n = n0 + it * 3 + gi;
    const bool v = active && (n < nEnd);
    const int nc = v ? n : n0;
    const unsigned idxA = kbase + (unsigned)nc;
    const unsigned bA = tfbits(idxA);
    const unsigned bB = tfbits(idxA + BOFF);
    const float s2A = v ? (float)(2.0 * sdA[nc]) : -3e38f;
    const float s2B = v ? (float)(2.0 * sdB[nc]) : -3e38f;
    const float sA = s2A + gumbel32(bA);
    const float sB = s2B + gumbel32(bB);
    if (sA > m1A) { m2A = m1A; n2A = n1A; c2A = c1A; m1A = sA; n1A = n; c1A = bA; }
    else if (sA > m2A) { m2A = sA; n2A = n; c2A = bA; }
    if (sB > m1B) { m2B = m1B; n2B = n1B; c2B = c1B; m1B = sB; n1B = n; c1B = bB; }
    else if (sB > m2B) { m2B = sB; n2B = n; c2B = bB; }
  }

  // exact fp64 for the fp32 winner (+ runner-up iff ambiguous: gap < 1e-4 >> 1e-5 screen err)
  unsigned long long pbA = 0ull, pbB = 0ull;
  if (n1A >= 0) {
    pbA = packcell(2.0 * sdA[n1A] + gumbel64(c1A), n1A);
    if (n2A >= 0 && (m1A - m2A) < 1e-4f) {
      const unsigned long long u2 = packcell(2.0 * sdA[n2A] + gumbel64(c2A), n2A);
      if (u2 > pbA) pbA = u2;
    }
  }
  if (n1B >= 0) {
    pbB = packcell(2.0 * sdB[n1B] + gumbel64(c1B), n1B);
    if (n2B >= 0 && (m1B - m2B) < 1e-4f) {
      const unsigned long long u2 = packcell(2.0 * sdB[n2B] + gumbel64(c2B), n2B);
      if (u2 > pbB) pbB = u2;
    }
  }

  // fold gi slots (lanes +20, +40), then one atomic per (batch, k)
  #pragma unroll
  for (int sh = 20; sh <= 40; sh += 20) {
    const unsigned long long oA = __shfl(pbA, lane + sh, 64);
    const unsigned long long oB = __shfl(pbB, lane + sh, 64);
    if (lane < 20) {
      if (oA > pbA) pbA = oA;
      if (oB > pbB) pbB = oB;
    }
  }
  if (lane < 20 && pbA) atomicMax(&cells[p * 20 + lane], pbA);
  if (lane < 20 && pbB) atomicMax(&cells[(p + 32) * 20 + lane], pbB);
}

// ---------- epilogue (fp32): gather-V on the fly, scores, softmax over K, context ----------
__global__ __launch_bounds__(256) void kfinal(
    const float* __restrict__ ge, const float* __restrict__ Wv,
    const float* __restrict__ bv, const float* __restrict__ Qm,
    const unsigned long long* __restrict__ cells, float* __restrict__ out) {
  const int b = blockIdx.x;
  const int t = threadIdx.x;
  const int wv = t >> 6;
  const int lane = t & 63;
  __shared__ float sc[20];
  __shared__ float ctxp[4][128];
  const float2 qv = ((const float2*)(Qm + b * 128))[lane];
  const float2 bvv = ((const float2*)bv)[lane];
  float2 Vk[5];
  #pragma unroll
  for (int kk = 0; kk < 5; ++kk) {
    const int kkk = wv * 5 + kk;
    const unsigned long long cell = cells[b * 20 + kkk];
    const int n = 32767 - (int)(cell & 0x7FFFull);
    const float* gr = ge + (size_t)n * 256;
    float v0 = bvv.x, v1 = bvv.y;
    for (int f = 0; f < 256; f += 4) {
      const float4 gv = *(const float4*)(gr + f);   // uniform -> s_load
      const float2 w0 = ((const float2*)(Wv + (size_t)(f + 0) * 128))[lane];
      const float2 w1 = ((const float2*)(Wv + (size_t)(f + 1) * 128))[lane];
      const float2 w2_ = ((const float2*)(Wv + (size_t)(f + 2) * 128))[lane];
      const float2 w3 = ((const float2*)(Wv + (size_t)(f + 3) * 128))[lane];
      v0 = fmaf(gv.x, w0.x, v0); v1 = fmaf(gv.x, w0.y, v1);
      v0 = fmaf(gv.y, w1.x, v0); v1 = fmaf(gv.y, w1.y, v1);
      v0 = fmaf(gv.z, w2_.x, v0); v1 = fmaf(gv.z, w2_.y, v1);
      v0 = fmaf(gv.w, w3.x, v0); v1 = fmaf(gv.w, w3.y, v1);
    }
    Vk[kk] = make_float2(v0, v1);
    float pr = qv.x * v0 + qv.y * v1;
    #pragma unroll
    for (int off = 32; off; off >>= 1) pr += __shfl_xor(pr, off, 64);
    if (lane == 0) sc[kkk] = pr * 0.08838834764831845f;  // 1/sqrt(128)
  }
  __syncthreads();
  float m = -3.0e38f;
  #pragma unroll
  for (int i = 0; i < 20; ++i) m = fmaxf(m, sc[i]);
  float s = 0.f;
  #pragma unroll
  for (int i = 0; i < 20; ++i) s += expf(sc[i] - m);
  const float inv = 1.0f / s;
  float c0 = 0.f, c1 = 0.f;
  #pragma unroll
  for (int kk = 0; kk < 5; ++kk) {
    const float wk = expf(sc[wv * 5 + kk] - m) * inv;
    c0 = fmaf(wk, Vk[kk].x, c0);
    c1 = fmaf(wk, Vk[kk].y, c1);
  }
  ctxp[wv][2 * lane] = c0;
  ctxp[wv][2 * lane + 1] = c1;
  __syncthreads();
  if (t < 128)
    out[b * 128 + t] = (ctxp[0][t] + ctxp[1][t]) + (ctxp[2][t] + ctxp[3][t]);
}

extern "C" void kernel_launch(void* const* d_in, const int* in_sizes, int n_in,
                              void* d_out, int out_size, void* d_ws, size_t ws_size,
                              hipStream_t stream) {
  (void)in_sizes; (void)n_in; (void)out_size; (void)ws_size;
  const float* pe = (const float*)d_in[0];
  const float* ge = (const float*)d_in[1];
  const float* Wq = (const float*)d_in[2];
  const float* bq = (const float*)d_in[3];
  const float* Wk = (const float*)d_in[4];
  const float* bk = (const float*)d_in[5];
  const float* Wv = (const float*)d_in[6];
  const float* bvp = (const float*)d_in[7];
  const float* W1 = (const float*)d_in[8];
  const float* b1 = (const float*)d_in[9];
  const float* w2 = (const float*)d_in[10];
  // d_in[11] = b2: uniform over n -> cancels in argmax; absent from output path.

  char* w = (char*)d_ws;
  double* Wfd = (double*)w;                              // 262144 B
  double* qbT = (double*)(w + 262144);                   // 65536 B
  float* Qm = (float*)(w + 327680);                      // 32768 B
  unsigned long long* cells =
      (unsigned long long*)(w + 360448);                 // 10240 B
  double* kpd = (double*)(w + 370688);                   // 20,480,000 B
  double* simd = (double*)(w + 20850688);                // 10,240,000 B (~31.1 MB total)
  float* out = (float*)d_out;

  kprep<<<dim3(321), dim3(128), 0, stream>>>(pe, Wq, bq, Wk, bk, W1, b1,
                                             Wfd, qbT, Qm, cells);
  kgemm<<<dim3(1250), dim3(128), 0, stream>>>(ge, Wfd, kpd);
  ksim<<<dim3(313, 8), dim3(64), 0, stream>>>(kpd, qbT, w2, simd);
  ksel2<<<dim3(1976), dim3(256), 0, stream>>>(simd, cells);
  kfinal<<<dim3(64), dim3(256), 0, stream>>>(ge, Wv, bvp, Qm, cells, out);
}